// Round 1
// baseline (2294.263 us; speedup 1.0000x reference)
//
#include <hip/hip_runtime.h>
#include <hip/hip_bf16.h>
#include <math.h>

// Problem constants
#define B_TOT 65536
#define DDIM  256
#define SCALE 0.125f   // 64^-0.5

// bf16 helpers (bit-level RNE, avoids hip_bf16 API version drift)
static __device__ __forceinline__ unsigned short f2bf(float f) {
  unsigned int u = __float_as_uint(f);
  unsigned int lsb = (u >> 16) & 1u;
  u += 0x7fffu + lsb;
  return (unsigned short)(u >> 16);
}
static __device__ __forceinline__ float bf2f(unsigned short s) {
  return __uint_as_float(((unsigned int)s) << 16);
}

// K0: transpose W_proj [256,512] -> WpT [512,256], W_gate likewise.
// Tiny (1MB); uncoalesced reads are fine.
__global__ __launch_bounds__(256) void prep_kernel(
    const float* __restrict__ Wp, const float* __restrict__ Wg,
    float* __restrict__ WpT, float* __restrict__ WgT) {
  int t = blockIdx.x * 256 + threadIdx.x;   // 0 .. 262143
  int which = t >> 17;                      // 0: Wp, 1: Wg
  int i = t & 131071;
  int co = i & 255;
  int j = i >> 8;                           // 0..511
  const float* src = which ? Wg : Wp;
  float* dst = which ? WgT : WpT;
  dst[j * 256 + co] = src[co * 512 + j];
}

// K1: per 16-b tile: q = masked_center @ Wq^T (SCALE folded in), then
// v[b, h*256+c'] = sum_a q[b,h*64+a] * Wk[h,a,c'].  v written bf16.
__global__ __launch_bounds__(256) void qv_kernel(
    const float* __restrict__ center, const int* __restrict__ valid,
    const float* __restrict__ Wq, const float* __restrict__ Wk,
    unsigned short* __restrict__ v) {
  __shared__ float sC[16][256];
  __shared__ float sQ[16][128];
  int t = threadIdx.x;
  int b0 = blockIdx.x * 16;

  // load center tile, masked
  #pragma unroll
  for (int s = 0; s < 4; ++s) {
    int idx = t + s * 256;           // float4 chunk id, 1024 total
    int row = idx >> 6;              // 64 chunks per row
    int col = (idx & 63) * 4;
    float4 cv = *(const float4*)(center + (size_t)(b0 + row) * 256 + col);
    if (valid[b0 + row] == 0) { cv.x = 0.f; cv.y = 0.f; cv.z = 0.f; cv.w = 0.f; }
    *(float4*)&sC[row][col] = cv;
  }
  __syncthreads();

  // q phase: thread -> 2 hq x 4 b.  LDS reads are wave-uniform (broadcast).
  {
    int hg = t & 63, bg = t >> 6;
    int hq0 = hg * 2;
    float acc[4][2];
    #pragma unroll
    for (int i = 0; i < 4; ++i) { acc[i][0] = 0.f; acc[i][1] = 0.f; }
    for (int c = 0; c < 256; c += 4) {
      float4 w0 = *(const float4*)(Wq + (size_t)hq0 * 256 + c);
      float4 w1 = *(const float4*)(Wq + (size_t)(hq0 + 1) * 256 + c);
      #pragma unroll
      for (int i = 0; i < 4; ++i) {
        float4 a4 = *(const float4*)&sC[bg * 4 + i][c];
        acc[i][0] += a4.x * w0.x + a4.y * w0.y + a4.z * w0.z + a4.w * w0.w;
        acc[i][1] += a4.x * w1.x + a4.y * w1.y + a4.z * w1.z + a4.w * w1.w;
      }
    }
    #pragma unroll
    for (int i = 0; i < 4; ++i) {
      sQ[bg * 4 + i][hq0]     = acc[i][0] * SCALE;
      sQ[bg * 4 + i][hq0 + 1] = acc[i][1] * SCALE;
    }
  }
  __syncthreads();

  // v phase: thread -> 4 c' x 4 b x 2 heads, inner over a (chunks of 4)
  {
    int jg = t & 63, bg = t >> 6;
    int cp = jg * 4;
    float acc0[4][4], acc1[4][4];
    #pragma unroll
    for (int i = 0; i < 4; ++i)
      #pragma unroll
      for (int c = 0; c < 4; ++c) { acc0[i][c] = 0.f; acc1[i][c] = 0.f; }
    for (int a = 0; a < 64; a += 4) {
      float4 w0[4], w1[4];
      #pragma unroll
      for (int i = 0; i < 4; ++i) {
        w0[i] = *(const float4*)(Wk + (size_t)(a + i) * 256 + cp);
        w1[i] = *(const float4*)(Wk + (size_t)(64 + a + i) * 256 + cp);
      }
      #pragma unroll
      for (int bi = 0; bi < 4; ++bi) {
        float4 q0 = *(const float4*)&sQ[bg * 4 + bi][a];
        float4 q1 = *(const float4*)&sQ[bg * 4 + bi][64 + a];
        acc0[bi][0] += q0.x * w0[0].x + q0.y * w0[1].x + q0.z * w0[2].x + q0.w * w0[3].x;
        acc0[bi][1] += q0.x * w0[0].y + q0.y * w0[1].y + q0.z * w0[2].y + q0.w * w0[3].y;
        acc0[bi][2] += q0.x * w0[0].z + q0.y * w0[1].z + q0.z * w0[2].z + q0.w * w0[3].z;
        acc0[bi][3] += q0.x * w0[0].w + q0.y * w0[1].w + q0.z * w0[2].w + q0.w * w0[3].w;
        acc1[bi][0] += q1.x * w1[0].x + q1.y * w1[1].x + q1.z * w1[2].x + q1.w * w1[3].x;
        acc1[bi][1] += q1.x * w1[0].y + q1.y * w1[1].y + q1.z * w1[2].y + q1.w * w1[3].y;
        acc1[bi][2] += q1.x * w1[0].z + q1.y * w1[1].z + q1.z * w1[2].z + q1.w * w1[3].z;
        acc1[bi][3] += q1.x * w1[0].w + q1.y * w1[1].w + q1.z * w1[2].w + q1.w * w1[3].w;
      }
    }
    #pragma unroll
    for (int bi = 0; bi < 4; ++bi) {
      size_t bb = (size_t)(b0 + bg * 4 + bi);
      ushort4 u0, u1;
      u0.x = f2bf(acc0[bi][0]); u0.y = f2bf(acc0[bi][1]);
      u0.z = f2bf(acc0[bi][2]); u0.w = f2bf(acc0[bi][3]);
      u1.x = f2bf(acc1[bi][0]); u1.y = f2bf(acc1[bi][1]);
      u1.z = f2bf(acc1[bi][2]); u1.w = f2bf(acc1[bi][3]);
      *(ushort4*)(v + bb * 512 + cp) = u0;
      *(ushort4*)(v + bb * 512 + 256 + cp) = u1;
    }
  }
}

// K2: wave-per-b attention. neigh read ONCE (held in 16x float4 regs),
// scores via shfl-reduce, softmax, ctx, write multi bf16 [ctx_h0 | ctx_h1].
__global__ __launch_bounds__(256) void attn_kernel(
    const float* __restrict__ neigh, const float* __restrict__ conf,
    const unsigned short* __restrict__ v, unsigned short* __restrict__ multi) {
  int t = threadIdx.x;
  int lane = t & 63;
  size_t b = (size_t)blockIdx.x * 4 + (t >> 6);

  const unsigned short* vb = v + b * 512;
  ushort4 u0 = *(const ushort4*)(vb + 4 * lane);
  ushort4 u1 = *(const ushort4*)(vb + 256 + 4 * lane);
  float v0x = bf2f(u0.x), v0y = bf2f(u0.y), v0z = bf2f(u0.z), v0w = bf2f(u0.w);
  float v1x = bf2f(u1.x), v1y = bf2f(u1.y), v1z = bf2f(u1.z), v1w = bf2f(u1.w);

  float lc = 0.f;
  if (lane < 16) lc = logf(fmaxf(conf[b * 16 + lane], 1e-8f));

  const float* nb = neigh + b * 4096;
  float4 n[16];
  float s0[16], s1[16];
  #pragma unroll
  for (int k = 0; k < 16; ++k) {
    n[k] = *(const float4*)(nb + k * 256 + 4 * lane);
    float p0 = v0x * n[k].x + v0y * n[k].y + v0z * n[k].z + v0w * n[k].w;
    float p1 = v1x * n[k].x + v1y * n[k].y + v1z * n[k].z + v1w * n[k].w;
    #pragma unroll
    for (int m = 1; m < 64; m <<= 1) {
      p0 += __shfl_xor(p0, m, 64);
      p1 += __shfl_xor(p1, m, 64);
    }
    float lck = __shfl(lc, k, 64);
    s0[k] = p0 + lck;     // SCALE already folded into v via q
    s1[k] = p1 + lck;
  }
  float m0 = s0[0], m1 = s1[0];
  #pragma unroll
  for (int k = 1; k < 16; ++k) { m0 = fmaxf(m0, s0[k]); m1 = fmaxf(m1, s1[k]); }
  float sum0 = 0.f, sum1 = 0.f;
  #pragma unroll
  for (int k = 0; k < 16; ++k) {
    s0[k] = expf(s0[k] - m0); sum0 += s0[k];
    s1[k] = expf(s1[k] - m1); sum1 += s1[k];
  }
  float r0 = 1.f / sum0, r1 = 1.f / sum1;
  float c0x = 0.f, c0y = 0.f, c0z = 0.f, c0w = 0.f;
  float c1x = 0.f, c1y = 0.f, c1z = 0.f, c1w = 0.f;
  #pragma unroll
  for (int k = 0; k < 16; ++k) {
    float a0 = s0[k] * r0, a1 = s1[k] * r1;
    c0x += a0 * n[k].x; c0y += a0 * n[k].y; c0z += a0 * n[k].z; c0w += a0 * n[k].w;
    c1x += a1 * n[k].x; c1y += a1 * n[k].y; c1z += a1 * n[k].z; c1w += a1 * n[k].w;
  }
  unsigned short* mb = multi + b * 512;
  ushort4 o0, o1;
  o0.x = f2bf(c0x); o0.y = f2bf(c0y); o0.z = f2bf(c0z); o0.w = f2bf(c0w);
  o1.x = f2bf(c1x); o1.y = f2bf(c1y); o1.z = f2bf(c1z); o1.w = f2bf(c1w);
  *(ushort4*)(mb + 4 * lane) = o0;
  *(ushort4*)(mb + 256 + 4 * lane) = o1;
}

// K3: context = multi @ Wp^T; gate = sigmoid([center|context] @ Wg^T);
// out = gate*center + (1-gate)*context.  16-b tile, 4b x 4co per thread.
__global__ __launch_bounds__(256) void out_kernel(
    const unsigned short* __restrict__ multi, const float* __restrict__ center,
    const int* __restrict__ valid, const float* __restrict__ WpT,
    const float* __restrict__ WgT, float* __restrict__ out) {
  __shared__ float sM[16][512];
  __shared__ float sC[16][256];
  __shared__ float sX[16][256];
  int t = threadIdx.x;
  int b0 = blockIdx.x * 16;

  // load multi tile (bf16 -> f32)
  #pragma unroll
  for (int s = 0; s < 4; ++s) {
    int idx = t + s * 256;            // 8-bf16 chunk id, 1024 total
    uint4 mu = *(const uint4*)(multi + (size_t)b0 * 512 + (size_t)idx * 8);
    const unsigned short* pu = (const unsigned short*)&mu;
    int row = idx >> 6;               // 64 chunks per 512-row
    int col = (idx & 63) * 8;
    #pragma unroll
    for (int i = 0; i < 8; ++i) sM[row][col + i] = bf2f(pu[i]);
  }
  // load center tile, masked
  #pragma unroll
  for (int s = 0; s < 4; ++s) {
    int idx = t + s * 256;
    int row = idx >> 6;
    int col = (idx & 63) * 4;
    float4 cv = *(const float4*)(center + (size_t)(b0 + row) * 256 + col);
    if (valid[b0 + row] == 0) { cv.x = 0.f; cv.y = 0.f; cv.z = 0.f; cv.w = 0.f; }
    *(float4*)&sC[row][col] = cv;
  }
  __syncthreads();

  int cg = t & 63, bg = t >> 6;
  int co = cg * 4;

  // proj GEMM: context[b][co] = sum_j sM[b][j] * Wp[co][j]
  {
    float acc[4][4];
    #pragma unroll
    for (int i = 0; i < 4; ++i)
      #pragma unroll
      for (int c = 0; c < 4; ++c) acc[i][c] = 0.f;
    for (int j = 0; j < 512; j += 4) {
      float4 w0 = *(const float4*)(WpT + (size_t)(j + 0) * 256 + co);
      float4 w1 = *(const float4*)(WpT + (size_t)(j + 1) * 256 + co);
      float4 w2 = *(const float4*)(WpT + (size_t)(j + 2) * 256 + co);
      float4 w3 = *(const float4*)(WpT + (size_t)(j + 3) * 256 + co);
      #pragma unroll
      for (int bi = 0; bi < 4; ++bi) {
        float4 a4 = *(const float4*)&sM[bg * 4 + bi][j];
        acc[bi][0] += a4.x * w0.x + a4.y * w1.x + a4.z * w2.x + a4.w * w3.x;
        acc[bi][1] += a4.x * w0.y + a4.y * w1.y + a4.z * w2.y + a4.w * w3.y;
        acc[bi][2] += a4.x * w0.z + a4.y * w1.z + a4.z * w2.z + a4.w * w3.z;
        acc[bi][3] += a4.x * w0.w + a4.y * w1.w + a4.z * w2.w + a4.w * w3.w;
      }
    }
    #pragma unroll
    for (int bi = 0; bi < 4; ++bi) {
      float4 o; o.x = acc[bi][0]; o.y = acc[bi][1]; o.z = acc[bi][2]; o.w = acc[bi][3];
      *(float4*)&sX[bg * 4 + bi][co] = o;
    }
  }
  __syncthreads();

  // gate GEMM + combine
  {
    float g[4][4];
    #pragma unroll
    for (int i = 0; i < 4; ++i)
      #pragma unroll
      for (int c = 0; c < 4; ++c) g[i][c] = 0.f;
    for (int j = 0; j < 256; j += 4) {   // center half of W_gate
      float4 w0 = *(const float4*)(WgT + (size_t)(j + 0) * 256 + co);
      float4 w1 = *(const float4*)(WgT + (size_t)(j + 1) * 256 + co);
      float4 w2 = *(const float4*)(WgT + (size_t)(j + 2) * 256 + co);
      float4 w3 = *(const float4*)(WgT + (size_t)(j + 3) * 256 + co);
      #pragma unroll
      for (int bi = 0; bi < 4; ++bi) {
        float4 a4 = *(const float4*)&sC[bg * 4 + bi][j];
        g[bi][0] += a4.x * w0.x + a4.y * w1.x + a4.z * w2.x + a4.w * w3.x;
        g[bi][1] += a4.x * w0.y + a4.y * w1.y + a4.z * w2.y + a4.w * w3.y;
        g[bi][2] += a4.x * w0.z + a4.y * w1.z + a4.z * w2.z + a4.w * w3.z;
        g[bi][3] += a4.x * w0.w + a4.y * w1.w + a4.z * w2.w + a4.w * w3.w;
      }
    }
    for (int j = 0; j < 256; j += 4) {   // context half of W_gate
      float4 w0 = *(const float4*)(WgT + (size_t)(256 + j + 0) * 256 + co);
      float4 w1 = *(const float4*)(WgT + (size_t)(256 + j + 1) * 256 + co);
      float4 w2 = *(const float4*)(WgT + (size_t)(256 + j + 2) * 256 + co);
      float4 w3 = *(const float4*)(WgT + (size_t)(256 + j + 3) * 256 + co);
      #pragma unroll
      for (int bi = 0; bi < 4; ++bi) {
        float4 a4 = *(const float4*)&sX[bg * 4 + bi][j];
        g[bi][0] += a4.x * w0.x + a4.y * w1.x + a4.z * w2.x + a4.w * w3.x;
        g[bi][1] += a4.x * w0.y + a4.y * w1.y + a4.z * w2.y + a4.w * w3.y;
        g[bi][2] += a4.x * w0.z + a4.y * w1.z + a4.z * w2.z + a4.w * w3.z;
        g[bi][3] += a4.x * w0.w + a4.y * w1.w + a4.z * w2.w + a4.w * w3.w;
      }
    }
    #pragma unroll
    for (int bi = 0; bi < 4; ++bi) {
      float4 cen = *(const float4*)&sC[bg * 4 + bi][co];
      float4 ctx = *(const float4*)&sX[bg * 4 + bi][co];
      float4 o;
      float ga;
      ga = 1.f / (1.f + expf(-g[bi][0])); o.x = ga * cen.x + (1.f - ga) * ctx.x;
      ga = 1.f / (1.f + expf(-g[bi][1])); o.y = ga * cen.y + (1.f - ga) * ctx.y;
      ga = 1.f / (1.f + expf(-g[bi][2])); o.z = ga * cen.z + (1.f - ga) * ctx.z;
      ga = 1.f / (1.f + expf(-g[bi][3])); o.w = ga * cen.w + (1.f - ga) * ctx.w;
      *(float4*)(out + (size_t)(b0 + bg * 4 + bi) * 256 + co) = o;
    }
  }
}

extern "C" void kernel_launch(void* const* d_in, const int* in_sizes, int n_in,
                              void* d_out, int out_size, void* d_ws, size_t ws_size,
                              hipStream_t stream) {
  const float* center = (const float*)d_in[0];
  const float* neigh  = (const float*)d_in[1];
  const float* conf   = (const float*)d_in[2];
  const int*   valid  = (const int*)d_in[3];
  const float* Wq     = (const float*)d_in[4];
  const float* Wk     = (const float*)d_in[5];
  const float* Wp     = (const float*)d_in[6];
  const float* Wg     = (const float*)d_in[7];
  float* out = (float*)d_out;

  // workspace layout: WpT (512KB) | WgT (512KB) | v bf16 (64MB) | multi bf16 (64MB)
  char* ws = (char*)d_ws;
  float* WpT = (float*)ws;
  float* WgT = (float*)(ws + (512 << 10));
  unsigned short* v     = (unsigned short*)(ws + (1 << 20));
  unsigned short* multi = (unsigned short*)(ws + (1 << 20) + (size_t)B_TOT * 512 * 2);

  prep_kernel<<<1024, 256, 0, stream>>>(Wp, Wg, WpT, WgT);
  qv_kernel<<<B_TOT / 16, 256, 0, stream>>>(center, valid, Wq, Wk, v);
  attn_kernel<<<B_TOT / 4, 256, 0, stream>>>(neigh, conf, v, multi);
  out_kernel<<<B_TOT / 16, 256, 0, stream>>>(multi, center, valid, WpT, WgT, out);
}